// Round 11
// baseline (116.192 us; speedup 1.0000x reference)
//
#include <hip/hip_runtime.h>
#include <hip/hip_bf16.h>
#include <math.h>

#define D_LLM 768
#define DKH   1024   // d_keys * n_heads = 128*8
#define NH    8
#define DK    128
#define S_LEN 1000
#define S_PAD 1024
#define M_ROWS 12288 // B*N*T = 128*96
#define T_LEN 96
#define N_VARS 16

static constexpr float SCALE_EXP2 = (float)(0.08838834764831845 * 1.4426950408889634); // 1/sqrt(128)/ln2

typedef __attribute__((ext_vector_type(8))) _Float16 half8;
typedef __attribute__((ext_vector_type(2))) _Float16 half2v;
typedef __attribute__((ext_vector_type(4))) float f32x4;

__device__ __forceinline__ half2v pkrtz(float a, float b) {
    return __builtin_bit_cast(half2v, __builtin_amdgcn_cvt_pkrtz(a, b));
}

__device__ __forceinline__ void gload_lds16(const void* g, void* l) {
    __builtin_amdgcn_global_load_lds(
        (const __attribute__((address_space(1))) unsigned int*)g,
        (__attribute__((address_space(3))) unsigned int*)l, 16, 0, 0);
}

// ================= prep: vemb->f16 | Wv^T->f16 | Wo^T->f16 | Wksum =================
__global__ __launch_bounds__(256) void prep_kernel(const float* __restrict__ vemb,
                                                   const float* __restrict__ Wv,
                                                   const float* __restrict__ Wo,
                                                   const float* __restrict__ Wk,
                                                   const float* __restrict__ bk,
                                                   _Float16* __restrict__ Ab16,
                                                   _Float16* __restrict__ Wvt,
                                                   _Float16* __restrict__ Wot,
                                                   float* __restrict__ Wksum,
                                                   float* __restrict__ bksum) {
    __shared__ float tl[32][33];
    int blk = blockIdx.x, tid = threadIdx.x;
    if (blk < 768) {
        int i4 = (blk * 256 + tid) * 4;
        float4 v = make_float4(0.f, 0.f, 0.f, 0.f);
        if (i4 < S_LEN * D_LLM) v = *(const float4*)(vemb + i4);
        short4 o;
        o.x = __builtin_bit_cast(short, (_Float16)v.x);
        o.y = __builtin_bit_cast(short, (_Float16)v.y);
        o.z = __builtin_bit_cast(short, (_Float16)v.z);
        o.w = __builtin_bit_cast(short, (_Float16)v.w);
        *(short4*)(Ab16 + i4) = o;
    } else if (blk < 1536) {
        int tau = blk - 768;
        int k0 = (tau % 24) * 32, n0 = (tau / 24) * 32;
        int tx = tid & 31, ty = tid >> 5;
        #pragma unroll
        for (int p = 0; p < 4; ++p)
            tl[ty + p * 8][tx] = Wv[(size_t)(k0 + ty + p * 8) * DKH + n0 + tx];
        __syncthreads();
        #pragma unroll
        for (int p = 0; p < 4; ++p)
            Wvt[(size_t)(n0 + ty + p * 8) * D_LLM + k0 + tx] = (_Float16)tl[tx][ty + p * 8];
    } else if (blk < 2304) {
        int tau = blk - 1536;
        int k0 = (tau & 31) * 32, n0 = (tau >> 5) * 32;
        int tx = tid & 31, ty = tid >> 5;
        #pragma unroll
        for (int p = 0; p < 4; ++p)
            tl[ty + p * 8][tx] = Wo[(size_t)(k0 + ty + p * 8) * D_LLM + n0 + tx];
        __syncthreads();
        #pragma unroll
        for (int p = 0; p < 4; ++p)
            Wot[(size_t)(n0 + ty + p * 8) * DKH + k0 + tx] = (_Float16)tl[tx][ty + p * 8];
    } else {
        int blk2 = blk - 2304;
        int w = tid >> 6, lane = tid & 63;
        if (blk2 < 192) {
            int d = blk2 * 4 + w;
            const float* p = Wk + (size_t)d * DKH + lane * 16;
            float s = 0.f;
            #pragma unroll
            for (int i = 0; i < 4; ++i) {
                float4 v = *(const float4*)(p + i * 4);
                s += v.x + v.y + v.z + v.w;
            }
            s += __shfl_down(s, 4);
            s += __shfl_down(s, 2);
            s += __shfl_down(s, 1);
            if ((lane & 7) == 0) Wksum[d * NH + (lane >> 3)] = s;
        } else if (w == 0) {
            const float* p = bk + lane * 16;
            float s = 0.f;
            #pragma unroll
            for (int i = 0; i < 4; ++i) {
                float4 v = *(const float4*)(p + i * 4);
                s += v.x + v.y + v.z + v.w;
            }
            s += __shfl_down(s, 4);
            s += __shfl_down(s, 2);
            s += __shfl_down(s, 1);
            if ((lane & 7) == 0) bksum[lane >> 3] = s;
        }
    }
}

// ================= merged: ksum (blocks 0-255) + vproj (blocks 256-511) =================
__global__ __launch_bounds__(256) void kv_kernel(const float* __restrict__ src,
                                                 const float* __restrict__ Wksum,
                                                 const float* __restrict__ bksum,
                                                 float* __restrict__ Kpad,
                                                 const _Float16* __restrict__ A,
                                                 const _Float16* __restrict__ Bt,
                                                 const float* __restrict__ bias,
                                                 _Float16* __restrict__ Vt) {
    __shared__ _Float16 VAs[2][2048];
    __shared__ _Float16 VBs[2][2048];
    int tid = threadIdx.x;
    if (blockIdx.x < 256) {
        int w = tid >> 6, lane = tid & 63;
        int s = blockIdx.x * 4 + w;
        if (s >= S_LEN) {
            if (lane < 8) Kpad[lane * S_PAD + s] = 0.f;
            return;
        }
        const float* sp = src + (size_t)s * D_LLM + lane * 12;
        float xv[12];
        ((float4*)xv)[0] = *(const float4*)(sp);
        ((float4*)xv)[1] = *(const float4*)(sp + 4);
        ((float4*)xv)[2] = *(const float4*)(sp + 8);
        float a[8] = {0.f, 0.f, 0.f, 0.f, 0.f, 0.f, 0.f, 0.f};
        const float* wp = Wksum + lane * 12 * NH;
        #pragma unroll
        for (int i = 0; i < 12; ++i) {
            float4 wa = *(const float4*)(wp + i * 8);
            float4 wb = *(const float4*)(wp + i * 8 + 4);
            a[0] = fmaf(xv[i], wa.x, a[0]); a[1] = fmaf(xv[i], wa.y, a[1]);
            a[2] = fmaf(xv[i], wa.z, a[2]); a[3] = fmaf(xv[i], wa.w, a[3]);
            a[4] = fmaf(xv[i], wb.x, a[4]); a[5] = fmaf(xv[i], wb.y, a[5]);
            a[6] = fmaf(xv[i], wb.z, a[6]); a[7] = fmaf(xv[i], wb.w, a[7]);
        }
        #pragma unroll
        for (int off = 32; off > 0; off >>= 1) {
            #pragma unroll
            for (int hh = 0; hh < 8; ++hh) a[hh] += __shfl_xor(a[hh], off);
        }
        #pragma unroll
        for (int hh = 0; hh < 8; ++hh)
            if (lane == hh) Kpad[hh * S_PAD + s] = (a[hh] + bksum[hh]) * SCALE_EXP2;
        return;
    }
    int b2 = blockIdx.x - 256;
    int w = tid >> 6, lane = tid & 63;
    int bm0 = (b2 >> 4) * 64, bn0 = (b2 & 15) * 64;
    int lrow = tid >> 2, lcol = (tid & 3) * 8;
    const _Float16* ga = A + (size_t)(bm0 + lrow) * D_LLM + lcol;
    const _Float16* gb = Bt + (size_t)(bn0 + lrow) * D_LLM + lcol;

    f32x4 acc[2][2];
    #pragma unroll
    for (int m = 0; m < 2; ++m)
        #pragma unroll
        for (int n = 0; n < 2; ++n) acc[m][n] = (f32x4){0.f, 0.f, 0.f, 0.f};
    int sgrp = (lane >> 4) << 3;
    int arow = (w >> 1) * 32 + (lane & 15);
    int brow = (w & 1) * 32 + (lane & 15);

#define VSTAGE(buf, k0) do { \
        gload_lds16(ga + (k0), (char*)&VAs[buf][0] + w * 1024); \
        gload_lds16(gb + (k0), (char*)&VBs[buf][0] + w * 1024); } while (0)

    VSTAGE(0, 0);
    __syncthreads();
    #pragma unroll 2
    for (int tt = 0; tt < 24; ++tt) {
        int cur = tt & 1;
        if (tt < 23) VSTAGE(cur ^ 1, (tt + 1) * 32);
        const _Float16* Ac = &VAs[cur][0];
        const _Float16* Bc = &VBs[cur][0];
        half8 af[2], bf[2];
        #pragma unroll
        for (int m = 0; m < 2; ++m) af[m] = *(const half8*)(Ac + (arow + m * 16) * 32 + sgrp);
        #pragma unroll
        for (int n = 0; n < 2; ++n) bf[n] = *(const half8*)(Bc + (brow + n * 16) * 32 + sgrp);
        __builtin_amdgcn_s_setprio(1);
        #pragma unroll
        for (int m = 0; m < 2; ++m)
            #pragma unroll
            for (int n = 0; n < 2; ++n)
                acc[m][n] = __builtin_amdgcn_mfma_f32_16x16x32_f16(af[m], bf[n], acc[m][n], 0, 0, 0);
        __builtin_amdgcn_s_setprio(0);
        __syncthreads();
    }
#undef VSTAGE

    int rowoff = (lane >> 4) << 2;
    #pragma unroll
    for (int m = 0; m < 2; ++m) {
        #pragma unroll
        for (int n = 0; n < 2; ++n) {
            int c = bn0 + (w & 1) * 32 + n * 16 + (lane & 15);
            float b = bias[c];
            #pragma unroll
            for (int q = 0; q < 4; ++q) {
                int srow = bm0 + (w >> 1) * 32 + m * 16 + rowoff + q;
                float val = (srow < S_LEN) ? acc[m][n][q] + b : 0.f;
                Vt[(size_t)c * S_PAD + srow] = (_Float16)val;
            }
        }
    }
}

// ================= fused softmax + PV: 1-wave blocks, 64 rows/wave, barrier-free =================
// chunk = 32 s x 128 e = 8KB; LDS row = 64B (32 s); slot sl of e-row er holds s-seg sl^(er&3)
__global__ __launch_bounds__(64) void attn_mfma_kernel(const float* __restrict__ ts,
                                                       const float* __restrict__ Kpad,
                                                       const _Float16* __restrict__ Vt,
                                                       _Float16* __restrict__ attB) {
    __shared__ _Float16 Vs[2][4096];   // 2 x 8KB
    __shared__ float Krow[1024];       // this head's scaled K row (4KB)
    const int lane = threadIdx.x;
    const int h = blockIdx.y;
    const int m0 = blockIdx.x * 64;
    const int l15 = lane & 15, q = lane >> 4;
    char* VsB = (char*)&Vs[0][0];

    // Krow stage FIRST (oldest in vmcnt queue)
    const float* kg = Kpad + h * S_PAD;
    #pragma unroll
    for (int j = 0; j < 4; ++j)
        gload_lds16(kg + j * 256 + lane * 4, (char*)Krow + j * 1024);

    // V staging: e-row = j*16 + (lane>>2); s-seg = (lane&3) ^ ((lane>>2)&3)  [row-XOR swizzle]
    const int seg = (lane & 3) ^ ((lane >> 2) & 3);
    const _Float16* gsrc = Vt + (size_t)(h * DK + (lane >> 2)) * S_PAD + seg * 8;
#define STAGE(ck) do { \
        _Pragma("unroll") \
        for (int j = 0; j < 8; ++j) \
            gload_lds16(gsrc + (size_t)j * 16 * S_PAD + (ck) * 32, \
                        VsB + ((ck) & 1) * 8192 + j * 1024); } while (0)
    STAGE(0);
    STAGE(1);

    // ts reads (regs)
    float x[4];
    #pragma unroll
    for (int r = 0; r < 4; ++r) {
        int m = m0 + r * 16 + l15;
        int rr = m / T_LEN;
        float v = ts[((size_t)(rr >> 4) * T_LEN + (m % T_LEN)) * N_VARS + (rr & 15)];
        x[r] = (v != v) ? 0.f : v;
    }

    // wait Krow: 24 vm-ops issued; vmcnt(16) drains the oldest 8 (Krow is within first 8
    // regardless of ts hoist/sink since gload_lds order is preserved)
    asm volatile("s_waitcnt vmcnt(16)" ::: "memory");
    __builtin_amdgcn_sched_barrier(0);

    // per-head min/max from LDS Krow (includes zero pads -> still a valid upper bound)
    float mn = 3e38f, mx = -3e38f;
    #pragma unroll
    for (int j = 0; j < 4; ++j) {
        float4 k4 = *(const float4*)&Krow[lane * 16 + j * 4];
        mx = fmaxf(mx, fmaxf(fmaxf(k4.x, k4.y), fmaxf(k4.z, k4.w)));
        mn = fminf(mn, fminf(fminf(k4.x, k4.y), fminf(k4.z, k4.w)));
    }
    #pragma unroll
    for (int off = 32; off > 0; off >>= 1) {
        mx = fmaxf(mx, __shfl_xor(mx, off));
        mn = fminf(mn, __shfl_xor(mn, off));
    }

    float nm[4], wpadf[4];
    #pragma unroll
    for (int r = 0; r < 4; ++r) {
        nm[r] = -((x[r] >= 0.f) ? x[r] * mx : x[r] * mn);   // exact upper bound of x*kv
        half2v p = pkrtz(__builtin_amdgcn_exp2f(nm[r]), 0.f);
        wpadf[r] = (float)p[0];                             // pad weight, f16-rounded as MFMA sees it
    }

    f32x4 acc[4][8];
    #pragma unroll
    for (int r = 0; r < 4; ++r)
        #pragma unroll
        for (int e = 0; e < 8; ++e) acc[r][e] = (f32x4){0.f, 0.f, 0.f, 0.f};
    f32x4 accd[4];
    #pragma unroll
    for (int r = 0; r < 4; ++r) accd[r] = (f32x4){0.f, 0.f, 0.f, 0.f};
    half8 ones;
    #pragma unroll
    for (int j = 0; j < 8; ++j) ones[j] = (_Float16)1.0f;

#define CHUNK(kt) do { \
        const char* cb = VsB + ((kt) & 1) * 8192; \
        const float* kvp = Krow + (kt) * 32 + q * 8; \
        float4 ka = *(const float4*)kvp; \
        float4 kb = *(const float4*)(kvp + 4); \
        float kv[8] = {ka.x, ka.y, ka.z, ka.w, kb.x, kb.y, kb.z, kb.w}; \
        half8 afr[4]; \
        _Pragma("unroll") \
        for (int r = 0; r < 4; ++r) { \
            union { half8 v; half2v hh[4]; } u; \
            _Pragma("unroll") \
            for (int j = 0; j < 4; ++j) { \
                float w0 = __builtin_amdgcn_exp2f(fmaf(x[r], kv[2 * j], nm[r])); \
                float w1 = __builtin_amdgcn_exp2f(fmaf(x[r], kv[2 * j + 1], nm[r])); \
                u.hh[j] = pkrtz(w0, w1); \
            } \
            afr[r] = u.v; \
        } \
        _Pragma("unroll") \
        for (int et = 0; et < 8; ++et) { \
            half8 bfv = *(const half8*)(cb + (et * 16 + l15) * 64 + ((q ^ (l15 & 3)) << 4)); \
            _Pragma("unroll") \
            for (int r = 0; r < 4; ++r) \
                acc[r][et] = __builtin_amdgcn_mfma_f32_16x16x32_f16(afr[r], bfv, acc[r][et], 0, 0, 0); \
        } \
        _Pragma("unroll") \
        for (int r = 0; r < 4; ++r) \
            accd[r] = __builtin_amdgcn_mfma_f32_16x16x32_f16(afr[r], ones, accd[r], 0, 0, 0); } while (0)

    for (int kt = 0; kt < 30; ++kt) {
        asm volatile("s_waitcnt vmcnt(8)" ::: "memory");   // chunk kt landed; kt+1 in flight
        __builtin_amdgcn_sched_barrier(0);
        CHUNK(kt);
        asm volatile("s_waitcnt lgkmcnt(0)" ::: "memory"); // my reads of buf kt&1 retired
        __builtin_amdgcn_sched_barrier(0);
        STAGE(kt + 2);                                     // overwrite buf kt&1
    }
    asm volatile("s_waitcnt vmcnt(8)" ::: "memory");
    __builtin_amdgcn_sched_barrier(0);
    CHUNK(30);
    asm volatile("s_waitcnt vmcnt(0)" ::: "memory");
    __builtin_amdgcn_sched_barrier(0);
    CHUNK(31);
#undef CHUNK
#undef STAGE

    // epilogue: den = rowsum - 24 * wpad(row)   (24 pads, each weight exp2(nm) exactly)
    int rowoff = q << 2;
    #pragma unroll
    for (int r = 0; r < 4; ++r) {
        #pragma unroll
        for (int qq = 0; qq < 4; ++qq) {
            float wp = __shfl(wpadf[r], rowoff + qq);
            float den = accd[r][qq] - 24.f * wp;
            float inv = 1.f / den;
            int mrow = m0 + r * 16 + rowoff + qq;
            _Float16* op = attB + (size_t)mrow * DKH + h * DK + l15;
            #pragma unroll
            for (int et = 0; et < 8; ++et)
                op[et * 16] = (_Float16)(acc[r][et][qq] * inv);
        }
    }
}

// ================= out projection: 128x96 tiles, 3-buffer, 1 barrier/k-step =================
__global__ __launch_bounds__(256) void outproj_kernel(const _Float16* __restrict__ A,
                                                      const _Float16* __restrict__ Bt,
                                                      const float* __restrict__ bo,
                                                      float* __restrict__ C) {
    __shared__ _Float16 As[3][4096];   // 3 x 8KB
    __shared__ _Float16 Bs[3][3072];   // 3 x 6KB
    int wg = blockIdx.x;
    wg = (wg & 7) * 96 + (wg >> 3);            // bijective XCD chunking (768 % 8 == 0)
    int bx = wg & 7, by = wg >> 3;
    int t = threadIdx.x, w = t >> 6, lane = t & 63;
    int bm0 = by * 128, bn0 = bx * 96;
    int lrow = t >> 2, lcol = (t & 3) * 8;
    const _Float16* ga0 = A + (size_t)(bm0 + lrow) * DKH + lcol;
    const _Float16* ga1 = ga0 + (size_t)64 * DKH;
    const _Float16* gb0 = Bt + (size_t)(bn0 + lrow) * DKH + lcol;
    const _Float16* gb1 = gb0 + (size_t)64 * DKH;   // rows 64..95: waves 0-1 only

    f32x4 acc[4][3];
    #pragma unroll
    for (int m = 0; m < 4; ++m)
        #pragma unroll
        for (int n = 0; n < 3; ++n) acc[m][n] = (f32x4){0.f, 0.f, 0.f, 0.f};

    int sgrp = (lane >> 4) << 3;
    int arow = (w >> 1) * 64 + (lane & 15);
    int brow = (w & 1) * 48 + (lane & 15);

#define OSTAGE(bi, k0) do { \
        gload_lds16(ga0 + (k0), (char*)&As[bi][0] + w * 1024); \
        gload_lds16(ga1 + (k0), (char*)&As[bi][0] + 4096 + w * 1024); \
        gload_lds16(gb0 + (k0), (char*)&Bs[bi][0] + w * 1024); \
        if (w < 2) gload_lds16(gb1 + (k0), (char*)&Bs[bi][0] + 4096 + w * 1024); } while (0)

    OSTAGE(0, 0);
    OSTAGE(1, 32);
    #pragma unroll
    for (int kt = 0; kt < 32; ++kt) {
        if (kt == 31)   asm volatile("s_waitcnt vmcnt(0)" ::: "memory");
        else if (w < 2) asm volatile("s_waitcnt vmcnt(4)" ::: "memory");
        else            asm volatile("s_waitcnt vmcnt(3)" ::: "memory");
        __builtin_amdgcn_sched_barrier(0);
        __builtin_amdgcn_s_barrier();
        if (kt < 30) OSTAGE((kt + 2) % 3, (kt + 2) * 32);
        const _Float16* Ac = &As[kt % 3][0];
        const _Float16* Bc = &Bs[kt % 3][0];
        half8 af[4], bf[3];
        #pragma unroll
        for (int m = 0; m < 4; ++m) af[m] = *(const half8*)(Ac + (arow + m * 16) * 32 + sgrp);
        #pragma unroll
        for (int n = 0; n < 3; ++n) bf[n] = *(const half8*)(Bc + (brow + n * 16) * 32 + sgrp);
        __builtin_amdgcn_s_setprio(1);
        #pragma unroll
        for (int m = 0; m < 4; ++m)
            #pragma unroll
            for (int n = 0; n < 3; ++n)
                acc[m][n] = __builtin_amdgcn_mfma_f32_16x16x32_f16(af[m], bf[n], acc[m][n], 0, 0, 0);
        __builtin_amdgcn_s_setprio(0);
    }
#undef OSTAGE

    int rowoff = (lane >> 4) << 2;
    #pragma unroll
    for (int m = 0; m < 4; ++m) {
        #pragma unroll
        for (int n = 0; n < 3; ++n) {
            int col = bn0 + (w & 1) * 48 + n * 16 + (lane & 15);
            float b = bo[col];
            #pragma unroll
            for (int q = 0; q < 4; ++q) {
                int row = bm0 + (w >> 1) * 64 + m * 16 + rowoff + q;
                C[(size_t)row * D_LLM + col] = acc[m][n][q] + b;
            }
        }
    }
}

extern "C" void kernel_launch(void* const* d_in, const int* in_sizes, int n_in,
                              void* d_out, int out_size, void* d_ws, size_t ws_size,
                              hipStream_t stream) {
    const float* ts   = (const float*)d_in[0];
    const float* src  = (const float*)d_in[1];
    const float* vemb = (const float*)d_in[2];
    const float* Wk   = (const float*)d_in[3];
    const float* bk   = (const float*)d_in[4];
    const float* Wv   = (const float*)d_in[5];
    const float* bv   = (const float*)d_in[6];
    const float* Wo   = (const float*)d_in[7];
    const float* bo   = (const float*)d_in[8];
    float* out = (float*)d_out;

    float* ws = (float*)d_ws;
    float* Kpad   = ws;                               // 8192 f
    float* Wksum  = ws + 8192;                        // 6144 f
    float* bksum  = ws + 14336;                       // 16 f
    _Float16* Vt   = (_Float16*)(ws + 14592);         // 1024*1024 f16
    _Float16* Wot  = (_Float16*)(ws + 540672);        // 768*1024 f16
    _Float16* attB = (_Float16*)(ws + 936960);        // 12288*1024 f16
    _Float16* Ab16 = (_Float16*)(ws + 936960);        // aliases attB (dead before attn)
    _Float16* Wvt  = (_Float16*)(ws + 1330176);

    // 1) prep: vemb->f16, Wv^T, Wo^T, Wksum/bksum
    prep_kernel<<<2497, 256, 0, stream>>>(vemb, Wv, Wo, Wk, bk, Ab16, Wvt, Wot, Wksum, bksum);
    // 2) merged ksum + vproj
    kv_kernel<<<512, 256, 0, stream>>>(src, Wksum, bksum, Kpad, Ab16, Wvt, bv, Vt);
    // 3) fused softmax + PV (1-wave blocks, barrier-free counted-vmcnt)
    {
        dim3 g(192, NH);
        attn_mfma_kernel<<<g, 64, 0, stream>>>(ts, Kpad, Vt, attB);
    }
    // 4) out projection: [12288,1024]@[1024,768] + bo
    outproj_kernel<<<768, 256, 0, stream>>>(attB, Wot, bo, out);
}

// Round 12
// 98.167 us; speedup vs baseline: 1.1836x; 1.1836x over previous
//
#include <hip/hip_runtime.h>
#include <hip/hip_bf16.h>
#include <math.h>

#define D_LLM 768
#define DKH   1024   // d_keys * n_heads = 128*8
#define NH    8
#define DK    128
#define S_LEN 1000
#define S_PAD 1024
#define M_ROWS 12288 // B*N*T = 128*96
#define T_LEN 96
#define N_VARS 16

static constexpr float SCALE_EXP2 = (float)(0.08838834764831845 * 1.4426950408889634); // 1/sqrt(128)/ln2

typedef __attribute__((ext_vector_type(8))) _Float16 half8;
typedef __attribute__((ext_vector_type(2))) _Float16 half2v;
typedef __attribute__((ext_vector_type(4))) float f32x4;

__device__ __forceinline__ half2v pkrtz(float a, float b) {
    return __builtin_bit_cast(half2v, __builtin_amdgcn_cvt_pkrtz(a, b));
}

__device__ __forceinline__ void gload_lds16(const void* g, void* l) {
    __builtin_amdgcn_global_load_lds(
        (const __attribute__((address_space(1))) unsigned int*)g,
        (__attribute__((address_space(3))) unsigned int*)l, 16, 0, 0);
}

// ================= prep: vemb->f16 | Wv^T->f16 | Wo^T->f16 | Wksum =================
__global__ __launch_bounds__(256) void prep_kernel(const float* __restrict__ vemb,
                                                   const float* __restrict__ Wv,
                                                   const float* __restrict__ Wo,
                                                   const float* __restrict__ Wk,
                                                   const float* __restrict__ bk,
                                                   _Float16* __restrict__ Ab16,
                                                   _Float16* __restrict__ Wvt,
                                                   _Float16* __restrict__ Wot,
                                                   float* __restrict__ Wksum,
                                                   float* __restrict__ bksum) {
    __shared__ float tl[32][33];
    int blk = blockIdx.x, tid = threadIdx.x;
    if (blk < 768) {
        int i4 = (blk * 256 + tid) * 4;
        float4 v = make_float4(0.f, 0.f, 0.f, 0.f);
        if (i4 < S_LEN * D_LLM) v = *(const float4*)(vemb + i4);
        short4 o;
        o.x = __builtin_bit_cast(short, (_Float16)v.x);
        o.y = __builtin_bit_cast(short, (_Float16)v.y);
        o.z = __builtin_bit_cast(short, (_Float16)v.z);
        o.w = __builtin_bit_cast(short, (_Float16)v.w);
        *(short4*)(Ab16 + i4) = o;
    } else if (blk < 1536) {
        int tau = blk - 768;
        int k0 = (tau % 24) * 32, n0 = (tau / 24) * 32;
        int tx = tid & 31, ty = tid >> 5;
        #pragma unroll
        for (int p = 0; p < 4; ++p)
            tl[ty + p * 8][tx] = Wv[(size_t)(k0 + ty + p * 8) * DKH + n0 + tx];
        __syncthreads();
        #pragma unroll
        for (int p = 0; p < 4; ++p)
            Wvt[(size_t)(n0 + ty + p * 8) * D_LLM + k0 + tx] = (_Float16)tl[tx][ty + p * 8];
    } else if (blk < 2304) {
        int tau = blk - 1536;
        int k0 = (tau & 31) * 32, n0 = (tau >> 5) * 32;
        int tx = tid & 31, ty = tid >> 5;
        #pragma unroll
        for (int p = 0; p < 4; ++p)
            tl[ty + p * 8][tx] = Wo[(size_t)(k0 + ty + p * 8) * D_LLM + n0 + tx];
        __syncthreads();
        #pragma unroll
        for (int p = 0; p < 4; ++p)
            Wot[(size_t)(n0 + ty + p * 8) * DKH + k0 + tx] = (_Float16)tl[tx][ty + p * 8];
    } else {
        int blk2 = blk - 2304;
        int w = tid >> 6, lane = tid & 63;
        if (blk2 < 192) {
            int d = blk2 * 4 + w;
            const float* p = Wk + (size_t)d * DKH + lane * 16;
            float s = 0.f;
            #pragma unroll
            for (int i = 0; i < 4; ++i) {
                float4 v = *(const float4*)(p + i * 4);
                s += v.x + v.y + v.z + v.w;
            }
            s += __shfl_down(s, 4);
            s += __shfl_down(s, 2);
            s += __shfl_down(s, 1);
            if ((lane & 7) == 0) Wksum[d * NH + (lane >> 3)] = s;
        } else if (w == 0) {
            const float* p = bk + lane * 16;
            float s = 0.f;
            #pragma unroll
            for (int i = 0; i < 4; ++i) {
                float4 v = *(const float4*)(p + i * 4);
                s += v.x + v.y + v.z + v.w;
            }
            s += __shfl_down(s, 4);
            s += __shfl_down(s, 2);
            s += __shfl_down(s, 1);
            if ((lane & 7) == 0) bksum[lane >> 3] = s;
        }
    }
}

// ================= merged: ksum (blocks 0-255) + vproj (blocks 256-511) =================
__global__ __launch_bounds__(256) void kv_kernel(const float* __restrict__ src,
                                                 const float* __restrict__ Wksum,
                                                 const float* __restrict__ bksum,
                                                 float* __restrict__ Kpad,
                                                 const _Float16* __restrict__ A,
                                                 const _Float16* __restrict__ Bt,
                                                 const float* __restrict__ bias,
                                                 _Float16* __restrict__ Vt) {
    __shared__ _Float16 VAs[2][2048];
    __shared__ _Float16 VBs[2][2048];
    int tid = threadIdx.x;
    if (blockIdx.x < 256) {
        int w = tid >> 6, lane = tid & 63;
        int s = blockIdx.x * 4 + w;
        if (s >= S_LEN) {
            if (lane < 8) Kpad[lane * S_PAD + s] = 0.f;
            return;
        }
        const float* sp = src + (size_t)s * D_LLM + lane * 12;
        float xv[12];
        ((float4*)xv)[0] = *(const float4*)(sp);
        ((float4*)xv)[1] = *(const float4*)(sp + 4);
        ((float4*)xv)[2] = *(const float4*)(sp + 8);
        float a[8] = {0.f, 0.f, 0.f, 0.f, 0.f, 0.f, 0.f, 0.f};
        const float* wp = Wksum + lane * 12 * NH;
        #pragma unroll
        for (int i = 0; i < 12; ++i) {
            float4 wa = *(const float4*)(wp + i * 8);
            float4 wb = *(const float4*)(wp + i * 8 + 4);
            a[0] = fmaf(xv[i], wa.x, a[0]); a[1] = fmaf(xv[i], wa.y, a[1]);
            a[2] = fmaf(xv[i], wa.z, a[2]); a[3] = fmaf(xv[i], wa.w, a[3]);
            a[4] = fmaf(xv[i], wb.x, a[4]); a[5] = fmaf(xv[i], wb.y, a[5]);
            a[6] = fmaf(xv[i], wb.z, a[6]); a[7] = fmaf(xv[i], wb.w, a[7]);
        }
        #pragma unroll
        for (int off = 32; off > 0; off >>= 1) {
            #pragma unroll
            for (int hh = 0; hh < 8; ++hh) a[hh] += __shfl_xor(a[hh], off);
        }
        #pragma unroll
        for (int hh = 0; hh < 8; ++hh)
            if (lane == hh) Kpad[hh * S_PAD + s] = (a[hh] + bksum[hh]) * SCALE_EXP2;
        return;
    }
    int b2 = blockIdx.x - 256;
    int w = tid >> 6, lane = tid & 63;
    int bm0 = (b2 >> 4) * 64, bn0 = (b2 & 15) * 64;
    int lrow = tid >> 2, lcol = (tid & 3) * 8;
    const _Float16* ga = A + (size_t)(bm0 + lrow) * D_LLM + lcol;
    const _Float16* gb = Bt + (size_t)(bn0 + lrow) * D_LLM + lcol;

    f32x4 acc[2][2];
    #pragma unroll
    for (int m = 0; m < 2; ++m)
        #pragma unroll
        for (int n = 0; n < 2; ++n) acc[m][n] = (f32x4){0.f, 0.f, 0.f, 0.f};
    int sgrp = (lane >> 4) << 3;
    int arow = (w >> 1) * 32 + (lane & 15);
    int brow = (w & 1) * 32 + (lane & 15);

#define VSTAGE(buf, k0) do { \
        gload_lds16(ga + (k0), (char*)&VAs[buf][0] + w * 1024); \
        gload_lds16(gb + (k0), (char*)&VBs[buf][0] + w * 1024); } while (0)

    VSTAGE(0, 0);
    __syncthreads();
    #pragma unroll 2
    for (int tt = 0; tt < 24; ++tt) {
        int cur = tt & 1;
        if (tt < 23) VSTAGE(cur ^ 1, (tt + 1) * 32);
        const _Float16* Ac = &VAs[cur][0];
        const _Float16* Bc = &VBs[cur][0];
        half8 af[2], bf[2];
        #pragma unroll
        for (int m = 0; m < 2; ++m) af[m] = *(const half8*)(Ac + (arow + m * 16) * 32 + sgrp);
        #pragma unroll
        for (int n = 0; n < 2; ++n) bf[n] = *(const half8*)(Bc + (brow + n * 16) * 32 + sgrp);
        __builtin_amdgcn_s_setprio(1);
        #pragma unroll
        for (int m = 0; m < 2; ++m)
            #pragma unroll
            for (int n = 0; n < 2; ++n)
                acc[m][n] = __builtin_amdgcn_mfma_f32_16x16x32_f16(af[m], bf[n], acc[m][n], 0, 0, 0);
        __builtin_amdgcn_s_setprio(0);
        __syncthreads();
    }
#undef VSTAGE

    int rowoff = (lane >> 4) << 2;
    #pragma unroll
    for (int m = 0; m < 2; ++m) {
        #pragma unroll
        for (int n = 0; n < 2; ++n) {
            int c = bn0 + (w & 1) * 32 + n * 16 + (lane & 15);
            float b = bias[c];
            #pragma unroll
            for (int q = 0; q < 4; ++q) {
                int srow = bm0 + (w >> 1) * 32 + m * 16 + rowoff + q;
                float val = (srow < S_LEN) ? acc[m][n][q] + b : 0.f;
                Vt[(size_t)c * S_PAD + srow] = (_Float16)val;
            }
        }
    }
}

// ---------------- per-head min/max of Kpad over s<1000 (scaled units) ----------------
__global__ __launch_bounds__(64) void kminmax_kernel(const float* __restrict__ Kpad,
                                                     float* __restrict__ mnmx) {
    int h = blockIdx.x, lane = threadIdx.x;
    float mx = -1e30f, mn = 1e30f;
    for (int s = lane; s < S_LEN; s += 64) {
        float v = Kpad[h * S_PAD + s];
        mx = fmaxf(mx, v); mn = fminf(mn, v);
    }
    #pragma unroll
    for (int off = 32; off > 0; off >>= 1) {
        mx = fmaxf(mx, __shfl_xor(mx, off));
        mn = fminf(mn, __shfl_xor(mn, off));
    }
    if (lane == 0) { mnmx[h * 2] = mn; mnmx[h * 2 + 1] = mx; }
}

// ================= fused softmax + PV (round-7 structure: f16 MFMA, counted-vmcnt) =================
__device__ __forceinline__ void compute_afr(const float* kq, float x0, float x1,
                                            float nm0, float nm1, half8& o0, half8& o1) {
    float4 a = *(const float4*)kq;
    float4 b = *(const float4*)(kq + 4);
    float kv[8] = {a.x, a.y, a.z, a.w, b.x, b.y, b.z, b.w};
    union { half8 v; half2v h[4]; } u0, u1;
    #pragma unroll
    for (int j = 0; j < 4; ++j) {
        float w00 = __builtin_amdgcn_exp2f(fmaf(x0, kv[2 * j], nm0));
        float w01 = __builtin_amdgcn_exp2f(fmaf(x0, kv[2 * j + 1], nm0));
        u0.h[j] = pkrtz(w00, w01);
        float w10 = __builtin_amdgcn_exp2f(fmaf(x1, kv[2 * j], nm1));
        float w11 = __builtin_amdgcn_exp2f(fmaf(x1, kv[2 * j + 1], nm1));
        u1.h[j] = pkrtz(w10, w11);
    }
    o0 = u0.v; o1 = u1.v;
}

__global__ __launch_bounds__(256) void attn_mfma_kernel(const float* __restrict__ ts,
                                                        const float* __restrict__ Kpad,
                                                        const float* __restrict__ mnmx,
                                                        const _Float16* __restrict__ Vt,
                                                        _Float16* __restrict__ attB) {
    __shared__ _Float16 Vs[2][8192];   // 2 x 16KB chunks (64 s x 128 e, XOR-swizzled rows)
    const int tid = threadIdx.x;
    const int lane = tid & 63, w = tid >> 6;
    const int h = blockIdx.y;
    const int m0 = (blockIdx.x * 4 + w) * 32;
    const int l15 = lane & 15, q = lane >> 4;

    const int erow = w * 8 + (lane >> 3);
    const int sgl = ((lane & 7) ^ (lane >> 3)) * 8;
    const _Float16* gsrc = Vt + (size_t)(h * DK + erow) * S_PAD + sgl;

    float mn = mnmx[h * 2], mx = mnmx[h * 2 + 1];
    float x0, x1, nm0, nm1;
    {
        int m = m0 + l15;
        int rr = m / T_LEN;
        float v = ts[((size_t)(rr >> 4) * T_LEN + (m % T_LEN)) * N_VARS + (rr & 15)];
        x0 = (v != v) ? 0.f : v;
        nm0 = -((x0 >= 0.f) ? x0 * mx : x0 * mn);
        m = m0 + 16 + l15;
        rr = m / T_LEN;
        v = ts[((size_t)(rr >> 4) * T_LEN + (m % T_LEN)) * N_VARS + (rr & 15)];
        x1 = (v != v) ? 0.f : v;
        nm1 = -((x1 >= 0.f) ? x1 * mx : x1 * mn);
    }
    // pad weight per row, rounded exactly as the MFMA saw it (rtz f16)
    float wpadf0, wpadf1;
    {
        half2v p0 = pkrtz(__builtin_amdgcn_exp2f(nm0), 0.f);
        half2v p1 = pkrtz(__builtin_amdgcn_exp2f(nm1), 0.f);
        wpadf0 = (float)p0[0];
        wpadf1 = (float)p1[0];
    }

    f32x4 acc0[8], acc1[8];
    #pragma unroll
    for (int e = 0; e < 8; ++e) {
        acc0[e] = (f32x4){0.f, 0.f, 0.f, 0.f};
        acc1[e] = (f32x4){0.f, 0.f, 0.f, 0.f};
    }
    f32x4 accd0 = (f32x4){0.f, 0.f, 0.f, 0.f};
    f32x4 accd1 = (f32x4){0.f, 0.f, 0.f, 0.f};
    half8 ones;
    #pragma unroll
    for (int j = 0; j < 8; ++j) ones[j] = (_Float16)1.0f;

    const float* kvp = Kpad + h * S_PAD + q * 8;
    half8 afrA0, afrA1, afrB0, afrB1;
    compute_afr(kvp, x0, x1, nm0, nm1, afrA0, afrA1);

    #pragma unroll
    for (int i = 0; i < 4; ++i)
        gload_lds16(gsrc + (size_t)(i * 32) * S_PAD, (char*)&Vs[0][0] + i * 4096 + w * 1024);
    #pragma unroll
    for (int i = 0; i < 4; ++i)
        gload_lds16(gsrc + (size_t)(i * 32) * S_PAD + 64, (char*)&Vs[1][0] + i * 4096 + w * 1024);
    asm volatile("s_waitcnt vmcnt(4)" ::: "memory");
    __builtin_amdgcn_s_barrier();

    const int bofs0 = l15 * 128 + ((q * 16) ^ ((l15 & 7) << 4));
    const int bofs1 = l15 * 128 + ((64 + q * 16) ^ ((l15 & 7) << 4));

#define PVSTEP(AF0, AF1, BOFS) do { \
        __builtin_amdgcn_s_setprio(1); \
        _Pragma("unroll") \
        for (int e = 0; e < 8; ++e) { \
            half8 bfv = *(const half8*)(cb + e * 2048 + (BOFS)); \
            acc0[e] = __builtin_amdgcn_mfma_f32_16x16x32_f16(AF0, bfv, acc0[e], 0, 0, 0); \
            acc1[e] = __builtin_amdgcn_mfma_f32_16x16x32_f16(AF1, bfv, acc1[e], 0, 0, 0); \
        } \
        accd0 = __builtin_amdgcn_mfma_f32_16x16x32_f16(AF0, ones, accd0, 0, 0, 0); \
        accd1 = __builtin_amdgcn_mfma_f32_16x16x32_f16(AF1, ones, accd1, 0, 0, 0); \
        __builtin_amdgcn_s_setprio(0); } while (0)

    #pragma unroll 2
    for (int kt = 0; kt < 16; ++kt) {
        const char* cb = (const char*)&Vs[0][0] + (kt & 1) * 16384;
        compute_afr(kvp + kt * 64 + 32, x0, x1, nm0, nm1, afrB0, afrB1);
        PVSTEP(afrA0, afrA1, bofs0);
        if (kt < 15) compute_afr(kvp + (kt + 1) * 64, x0, x1, nm0, nm1, afrA0, afrA1);
        PVSTEP(afrB0, afrB1, bofs1);
        __builtin_amdgcn_s_barrier();
        if (kt < 14) {
            #pragma unroll
            for (int i = 0; i < 4; ++i)
                gload_lds16(gsrc + (size_t)(i * 32) * S_PAD + (kt + 2) * 64,
                            (char*)&Vs[0][0] + (kt & 1) * 16384 + i * 4096 + w * 1024);
            asm volatile("s_waitcnt vmcnt(4)" ::: "memory");
        } else {
            asm volatile("s_waitcnt vmcnt(0)" ::: "memory");
        }
        __builtin_amdgcn_s_barrier();
    }
#undef PVSTEP

    // epilogue: den = rowsum - 24 * wpad(row)
    int rowoff = q << 2;
    #pragma unroll
    for (int r = 0; r < 2; ++r) {
        #pragma unroll
        for (int qq = 0; qq < 4; ++qq) {
            float wp = __shfl(r ? wpadf1 : wpadf0, rowoff + qq);
            float den = (r ? accd1[qq] : accd0[qq]) - 24.f * wp;
            float inv = 1.f / den;
            int mrow = m0 + r * 16 + rowoff + qq;
            _Float16* op = attB + (size_t)mrow * DKH + h * DK + l15;
            #pragma unroll
            for (int e = 0; e < 8; ++e)
                op[e * 16] = (_Float16)((r ? acc1[e][qq] : acc0[e][qq]) * inv);
        }
    }
}

// ================= out projection: 128x96 tiles, 3-buffer, 1 barrier/k-step =================
__global__ __launch_bounds__(256) void outproj_kernel(const _Float16* __restrict__ A,
                                                      const _Float16* __restrict__ Bt,
                                                      const float* __restrict__ bo,
                                                      float* __restrict__ C) {
    __shared__ _Float16 As[3][4096];   // 3 x 8KB
    __shared__ _Float16 Bs[3][3072];   // 3 x 6KB
    int wg = blockIdx.x;
    wg = (wg & 7) * 96 + (wg >> 3);            // bijective XCD chunking (768 % 8 == 0)
    int bx = wg & 7, by = wg >> 3;
    int t = threadIdx.x, w = t >> 6, lane = t & 63;
    int bm0 = by * 128, bn0 = bx * 96;
    int lrow = t >> 2, lcol = (t & 3) * 8;
    const _Float16* ga0 = A + (size_t)(bm0 + lrow) * DKH + lcol;
    const _Float16* ga1 = ga0 + (size_t)64 * DKH;
    const _Float16* gb0 = Bt + (size_t)(bn0 + lrow) * DKH + lcol;
    const _Float16* gb1 = gb0 + (size_t)64 * DKH;   // rows 64..95: waves 0-1 only

    f32x4 acc[4][3];
    #pragma unroll
    for (int m = 0; m < 4; ++m)
        #pragma unroll
        for (int n = 0; n < 3; ++n) acc[m][n] = (f32x4){0.f, 0.f, 0.f, 0.f};

    int sgrp = (lane >> 4) << 3;
    int arow = (w >> 1) * 64 + (lane & 15);
    int brow = (w & 1) * 48 + (lane & 15);

#define OSTAGE(bi, k0) do { \
        gload_lds16(ga0 + (k0), (char*)&As[bi][0] + w * 1024); \
        gload_lds16(ga1 + (k0), (char*)&As[bi][0] + 4096 + w * 1024); \
        gload_lds16(gb0 + (k0), (char*)&Bs[bi][0] + w * 1024); \
        if (w < 2) gload_lds16(gb1 + (k0), (char*)&Bs[bi][0] + 4096 + w * 1024); } while (0)

    OSTAGE(0, 0);
    OSTAGE(1, 32);
    #pragma unroll
    for (int kt = 0; kt < 32; ++kt) {
        if (kt == 31)   asm volatile("s_waitcnt vmcnt(0)" ::: "memory");
        else if (w < 2) asm volatile("s_waitcnt vmcnt(4)" ::: "memory");
        else            asm volatile("s_waitcnt vmcnt(3)" ::: "memory");
        __builtin_amdgcn_sched_barrier(0);
        __builtin_amdgcn_s_barrier();
        if (kt < 30) OSTAGE((kt + 2) % 3, (kt + 2) * 32);
        const _Float16* Ac = &As[kt % 3][0];
        const _Float16* Bc = &Bs[kt % 3][0];
        half8 af[4], bf[3];
        #pragma unroll
        for (int m = 0; m < 4; ++m) af[m] = *(const half8*)(Ac + (arow + m * 16) * 32 + sgrp);
        #pragma unroll
        for (int n = 0; n < 3; ++n) bf[n] = *(const half8*)(Bc + (brow + n * 16) * 32 + sgrp);
        __builtin_amdgcn_s_setprio(1);
        #pragma unroll
        for (int m = 0; m < 4; ++m)
            #pragma unroll
            for (int n = 0; n < 3; ++n)
                acc[m][n] = __builtin_amdgcn_mfma_f32_16x16x32_f16(af[m], bf[n], acc[m][n], 0, 0, 0);
        __builtin_amdgcn_s_setprio(0);
    }
#undef OSTAGE

    int rowoff = (lane >> 4) << 2;
    #pragma unroll
    for (int m = 0; m < 4; ++m) {
        #pragma unroll
        for (int n = 0; n < 3; ++n) {
            int col = bn0 + (w & 1) * 48 + n * 16 + (lane & 15);
            float b = bo[col];
            #pragma unroll
            for (int q = 0; q < 4; ++q) {
                int row = bm0 + (w >> 1) * 64 + m * 16 + rowoff + q;
                C[(size_t)row * D_LLM + col] = acc[m][n][q] + b;
            }
        }
    }
}

extern "C" void kernel_launch(void* const* d_in, const int* in_sizes, int n_in,
                              void* d_out, int out_size, void* d_ws, size_t ws_size,
                              hipStream_t stream) {
    const float* ts   = (const float*)d_in[0];
    const float* src  = (const float*)d_in[1];
    const float* vemb = (const float*)d_in[2];
    const float* Wk   = (const float*)d_in[3];
    const float* bk   = (const float*)d_in[4];
    const float* Wv   = (const float*)d_in[5];
    const float* bv   = (const float*)d_in[6];
    const float* Wo   = (const float*)d_in[7];
    const float* bo   = (const float*)d_in[8];
    float* out = (float*)d_out;

    float* ws = (float*)d_ws;
    float* Kpad   = ws;                               // 8192 f
    float* Wksum  = ws + 8192;                        // 6144 f
    float* bksum  = ws + 14336;                       // 16 f
    float* mnmx   = ws + 14352;                       // 16 f
    _Float16* Vt   = (_Float16*)(ws + 14592);         // 1024*1024 f16
    _Float16* Wot  = (_Float16*)(ws + 540672);        // 768*1024 f16
    _Float16* attB = (_Float16*)(ws + 936960);        // 12288*1024 f16
    _Float16* Ab16 = (_Float16*)(ws + 936960);        // aliases attB (dead before attn)
    _Float16* Wvt  = (_Float16*)(ws + 1330176);

    // 1) prep: vemb->f16, Wv^T, Wo^T, Wksum/bksum
    prep_kernel<<<2497, 256, 0, stream>>>(vemb, Wv, Wo, Wk, bk, Ab16, Wvt, Wot, Wksum, bksum);
    // 2) merged ksum + vproj
    kv_kernel<<<512, 256, 0, stream>>>(src, Wksum, bksum, Kpad, Ab16, Wvt, bv, Vt);
    // 3) per-head min/max (exact max-subtraction)
    kminmax_kernel<<<8, 64, 0, stream>>>(Kpad, mnmx);
    // 4) fused softmax + PV (round-7 structure)
    {
        dim3 g(96, NH);
        attn_mfma_kernel<<<g, 256, 0, stream>>>(ts, Kpad, mnmx, Vt, attB);
    }
    // 5) out projection: [12288,1024]@[1024,768] + bo
    outproj_kernel<<<768, 256, 0, stream>>>(attB, Wot, bo, out);
}

// Round 13
// 87.723 us; speedup vs baseline: 1.3245x; 1.1191x over previous
//
#include <hip/hip_runtime.h>
#include <hip/hip_bf16.h>
#include <math.h>

#define D_LLM 768
#define DKH   1024   // d_keys * n_heads = 128*8
#define NH    8
#define DK    128
#define S_LEN 1000
#define S_PAD 1024
#define M_ROWS 12288 // B*N*T = 128*96
#define T_LEN 96
#define N_VARS 16

static constexpr float SCALE_EXP2 = (float)(0.08838834764831845 * 1.4426950408889634); // 1/sqrt(128)/ln2

typedef __attribute__((ext_vector_type(8))) _Float16 half8;
typedef __attribute__((ext_vector_type(2))) _Float16 half2v;
typedef __attribute__((ext_vector_type(4))) float f32x4;

__device__ __forceinline__ half2v pkrtz(float a, float b) {
    return __builtin_bit_cast(half2v, __builtin_amdgcn_cvt_pkrtz(a, b));
}

__device__ __forceinline__ void gload_lds16(const void* g, void* l) {
    __builtin_amdgcn_global_load_lds(
        (const __attribute__((address_space(1))) unsigned int*)g,
        (__attribute__((address_space(3))) unsigned int*)l, 16, 0, 0);
}

// ================= prep: vemb->f16 | Wv^T->f16 | Wo^T->f16 | Wksum =================
__global__ __launch_bounds__(256) void prep_kernel(const float* __restrict__ vemb,
                                                   const float* __restrict__ Wv,
                                                   const float* __restrict__ Wo,
                                                   const float* __restrict__ Wk,
                                                   const float* __restrict__ bk,
                                                   _Float16* __restrict__ Ab16,
                                                   _Float16* __restrict__ Wvt,
                                                   _Float16* __restrict__ Wot,
                                                   float* __restrict__ Wksum,
                                                   float* __restrict__ bksum) {
    __shared__ float tl[32][33];
    int blk = blockIdx.x, tid = threadIdx.x;
    if (blk < 768) {
        int i4 = (blk * 256 + tid) * 4;
        float4 v = make_float4(0.f, 0.f, 0.f, 0.f);
        if (i4 < S_LEN * D_LLM) v = *(const float4*)(vemb + i4);
        short4 o;
        o.x = __builtin_bit_cast(short, (_Float16)v.x);
        o.y = __builtin_bit_cast(short, (_Float16)v.y);
        o.z = __builtin_bit_cast(short, (_Float16)v.z);
        o.w = __builtin_bit_cast(short, (_Float16)v.w);
        *(short4*)(Ab16 + i4) = o;
    } else if (blk < 1536) {
        int tau = blk - 768;
        int k0 = (tau % 24) * 32, n0 = (tau / 24) * 32;
        int tx = tid & 31, ty = tid >> 5;
        #pragma unroll
        for (int p = 0; p < 4; ++p)
            tl[ty + p * 8][tx] = Wv[(size_t)(k0 + ty + p * 8) * DKH + n0 + tx];
        __syncthreads();
        #pragma unroll
        for (int p = 0; p < 4; ++p)
            Wvt[(size_t)(n0 + ty + p * 8) * D_LLM + k0 + tx] = (_Float16)tl[tx][ty + p * 8];
    } else if (blk < 2304) {
        int tau = blk - 1536;
        int k0 = (tau & 31) * 32, n0 = (tau >> 5) * 32;
        int tx = tid & 31, ty = tid >> 5;
        #pragma unroll
        for (int p = 0; p < 4; ++p)
            tl[ty + p * 8][tx] = Wo[(size_t)(k0 + ty + p * 8) * D_LLM + n0 + tx];
        __syncthreads();
        #pragma unroll
        for (int p = 0; p < 4; ++p)
            Wot[(size_t)(n0 + ty + p * 8) * DKH + k0 + tx] = (_Float16)tl[tx][ty + p * 8];
    } else {
        int blk2 = blk - 2304;
        int w = tid >> 6, lane = tid & 63;
        if (blk2 < 192) {
            int d = blk2 * 4 + w;
            const float* p = Wk + (size_t)d * DKH + lane * 16;
            float s = 0.f;
            #pragma unroll
            for (int i = 0; i < 4; ++i) {
                float4 v = *(const float4*)(p + i * 4);
                s += v.x + v.y + v.z + v.w;
            }
            s += __shfl_down(s, 4);
            s += __shfl_down(s, 2);
            s += __shfl_down(s, 1);
            if ((lane & 7) == 0) Wksum[d * NH + (lane >> 3)] = s;
        } else if (w == 0) {
            const float* p = bk + lane * 16;
            float s = 0.f;
            #pragma unroll
            for (int i = 0; i < 4; ++i) {
                float4 v = *(const float4*)(p + i * 4);
                s += v.x + v.y + v.z + v.w;
            }
            s += __shfl_down(s, 4);
            s += __shfl_down(s, 2);
            s += __shfl_down(s, 1);
            if ((lane & 7) == 0) bksum[lane >> 3] = s;
        }
    }
}

// ================= merged: ksum (blocks 0-255) + vproj (blocks 256-511) =================
__global__ __launch_bounds__(256) void kv_kernel(const float* __restrict__ src,
                                                 const float* __restrict__ Wksum,
                                                 const float* __restrict__ bksum,
                                                 float* __restrict__ Kpad,
                                                 const _Float16* __restrict__ A,
                                                 const _Float16* __restrict__ Bt,
                                                 const float* __restrict__ bias,
                                                 _Float16* __restrict__ Vt) {
    __shared__ _Float16 VAs[2][2048];
    __shared__ _Float16 VBs[2][2048];
    int tid = threadIdx.x;
    if (blockIdx.x < 256) {
        // ---- ksum: Kpad[h][s] = (src[s,:].Wksum[:,h] + bksum[h]) * SCALE_EXP2 ----
        int w = tid >> 6, lane = tid & 63;
        int s = blockIdx.x * 4 + w;
        if (s >= S_LEN) {
            if (lane < 8) Kpad[lane * S_PAD + s] = 0.f;
            return;
        }
        const float* sp = src + (size_t)s * D_LLM + lane * 12;
        float xv[12];
        ((float4*)xv)[0] = *(const float4*)(sp);
        ((float4*)xv)[1] = *(const float4*)(sp + 4);
        ((float4*)xv)[2] = *(const float4*)(sp + 8);
        float a[8] = {0.f, 0.f, 0.f, 0.f, 0.f, 0.f, 0.f, 0.f};
        const float* wp = Wksum + lane * 12 * NH;
        #pragma unroll
        for (int i = 0; i < 12; ++i) {
            float4 wa = *(const float4*)(wp + i * 8);
            float4 wb = *(const float4*)(wp + i * 8 + 4);
            a[0] = fmaf(xv[i], wa.x, a[0]); a[1] = fmaf(xv[i], wa.y, a[1]);
            a[2] = fmaf(xv[i], wa.z, a[2]); a[3] = fmaf(xv[i], wa.w, a[3]);
            a[4] = fmaf(xv[i], wb.x, a[4]); a[5] = fmaf(xv[i], wb.y, a[5]);
            a[6] = fmaf(xv[i], wb.z, a[6]); a[7] = fmaf(xv[i], wb.w, a[7]);
        }
        #pragma unroll
        for (int off = 32; off > 0; off >>= 1) {
            #pragma unroll
            for (int hh = 0; hh < 8; ++hh) a[hh] += __shfl_xor(a[hh], off);
        }
        #pragma unroll
        for (int hh = 0; hh < 8; ++hh)
            if (lane == hh) Kpad[hh * S_PAD + s] = (a[hh] + bksum[hh]) * SCALE_EXP2;
        return;
    }
    // ---- vproj: 64x64 tiles ----
    int b2 = blockIdx.x - 256;
    int w = tid >> 6, lane = tid & 63;
    int bm0 = (b2 >> 4) * 64, bn0 = (b2 & 15) * 64;
    int lrow = tid >> 2, lcol = (tid & 3) * 8;
    const _Float16* ga = A + (size_t)(bm0 + lrow) * D_LLM + lcol;
    const _Float16* gb = Bt + (size_t)(bn0 + lrow) * D_LLM + lcol;

    f32x4 acc[2][2];
    #pragma unroll
    for (int m = 0; m < 2; ++m)
        #pragma unroll
        for (int n = 0; n < 2; ++n) acc[m][n] = (f32x4){0.f, 0.f, 0.f, 0.f};
    int sgrp = (lane >> 4) << 3;
    int arow = (w >> 1) * 32 + (lane & 15);
    int brow = (w & 1) * 32 + (lane & 15);

#define VSTAGE(buf, k0) do { \
        gload_lds16(ga + (k0), (char*)&VAs[buf][0] + w * 1024); \
        gload_lds16(gb + (k0), (char*)&VBs[buf][0] + w * 1024); } while (0)

    VSTAGE(0, 0);
    __syncthreads();
    #pragma unroll 2
    for (int tt = 0; tt < 24; ++tt) {
        int cur = tt & 1;
        if (tt < 23) VSTAGE(cur ^ 1, (tt + 1) * 32);
        const _Float16* Ac = &VAs[cur][0];
        const _Float16* Bc = &VBs[cur][0];
        half8 af[2], bf[2];
        #pragma unroll
        for (int m = 0; m < 2; ++m) af[m] = *(const half8*)(Ac + (arow + m * 16) * 32 + sgrp);
        #pragma unroll
        for (int n = 0; n < 2; ++n) bf[n] = *(const half8*)(Bc + (brow + n * 16) * 32 + sgrp);
        __builtin_amdgcn_s_setprio(1);
        #pragma unroll
        for (int m = 0; m < 2; ++m)
            #pragma unroll
            for (int n = 0; n < 2; ++n)
                acc[m][n] = __builtin_amdgcn_mfma_f32_16x16x32_f16(af[m], bf[n], acc[m][n], 0, 0, 0);
        __builtin_amdgcn_s_setprio(0);
        __syncthreads();
    }
#undef VSTAGE

    int rowoff = (lane >> 4) << 2;
    #pragma unroll
    for (int m = 0; m < 2; ++m) {
        #pragma unroll
        for (int n = 0; n < 2; ++n) {
            int c = bn0 + (w & 1) * 32 + n * 16 + (lane & 15);
            float b = bias[c];
            #pragma unroll
            for (int q = 0; q < 4; ++q) {
                int srow = bm0 + (w >> 1) * 32 + m * 16 + rowoff + q;
                float val = (srow < S_LEN) ? acc[m][n][q] + b : 0.f;
                Vt[(size_t)c * S_PAD + srow] = (_Float16)val;
            }
        }
    }
}

// ================= fused softmax + PV: 3-buffer, 1 barrier/chunk, LDS-resident K-row =================
__device__ __forceinline__ void compute_afr(const float* kq, float x0, float x1,
                                            float nm0, float nm1, half8& o0, half8& o1) {
    float4 a = *(const float4*)kq;        // ds_read_b128 (LDS)
    float4 b = *(const float4*)(kq + 4);
    float kv[8] = {a.x, a.y, a.z, a.w, b.x, b.y, b.z, b.w};
    union { half8 v; half2v h[4]; } u0, u1;
    #pragma unroll
    for (int j = 0; j < 4; ++j) {
        float w00 = __builtin_amdgcn_exp2f(fmaf(x0, kv[2 * j], nm0));
        float w01 = __builtin_amdgcn_exp2f(fmaf(x0, kv[2 * j + 1], nm0));
        u0.h[j] = pkrtz(w00, w01);
        float w10 = __builtin_amdgcn_exp2f(fmaf(x1, kv[2 * j], nm1));
        float w11 = __builtin_amdgcn_exp2f(fmaf(x1, kv[2 * j + 1], nm1));
        u1.h[j] = pkrtz(w10, w11);
    }
    o0 = u0.v; o1 = u1.v;
}

__global__ __launch_bounds__(256) void attn_mfma_kernel(const float* __restrict__ ts,
                                                        const float* __restrict__ Kpad,
                                                        const _Float16* __restrict__ Vt,
                                                        _Float16* __restrict__ attB) {
    __shared__ _Float16 Vs[3][8192];   // 3 x 16KB chunks (64 s x 128 e, XOR-swizzled rows)
    __shared__ float Krow[1024];       // this head's scaled K row (4KB)
    __shared__ float red[8];
    const int tid = threadIdx.x;
    const int lane = tid & 63, w = tid >> 6;
    const int h = blockIdx.y;
    const int m0 = (blockIdx.x * 4 + w) * 32;
    const int l15 = lane & 15, q = lane >> 4;

    const int erow = w * 8 + (lane >> 3);
    const int sgl = ((lane & 7) ^ (lane >> 3)) * 8;
    const _Float16* gsrc = Vt + (size_t)(h * DK + erow) * S_PAD + sgl;
    const float* kg = Kpad + h * S_PAD;

    // issue Krow stage first (oldest), then V chunks 0,1
    gload_lds16(kg + w * 256 + lane * 4, (char*)Krow + w * 1024);
    #pragma unroll
    for (int i = 0; i < 4; ++i)
        gload_lds16(gsrc + (size_t)(i * 32) * S_PAD, (char*)&Vs[0][0] + i * 4096 + w * 1024);
    #pragma unroll
    for (int i = 0; i < 4; ++i)
        gload_lds16(gsrc + (size_t)(i * 32) * S_PAD + 64, (char*)&Vs[1][0] + i * 4096 + w * 1024);

    float x0, x1;
    {
        int m = m0 + l15;
        int rr = m / T_LEN;
        float v = ts[((size_t)(rr >> 4) * T_LEN + (m % T_LEN)) * N_VARS + (rr & 15)];
        x0 = (v != v) ? 0.f : v;
        m = m0 + 16 + l15;
        rr = m / T_LEN;
        v = ts[((size_t)(rr >> 4) * T_LEN + (m % T_LEN)) * N_VARS + (rr & 15)];
        x1 = (v != v) ? 0.f : v;
    }

    asm volatile("s_waitcnt vmcnt(8)" ::: "memory");   // Krow landed (V chunks may still fly)
    __builtin_amdgcn_sched_barrier(0);
    __builtin_amdgcn_s_barrier();

    // per-head min/max from LDS row (s<1000 only; pads are 0)
    float mn, mx;
    {
        float4 k4 = *(const float4*)&Krow[tid * 4];
        if (tid < 250) {
            mx = fmaxf(fmaxf(k4.x, k4.y), fmaxf(k4.z, k4.w));
            mn = fminf(fminf(k4.x, k4.y), fminf(k4.z, k4.w));
        } else { mx = -3e38f; mn = 3e38f; }
        #pragma unroll
        for (int off = 32; off > 0; off >>= 1) {
            mx = fmaxf(mx, __shfl_xor(mx, off));
            mn = fminf(mn, __shfl_xor(mn, off));
        }
        if (lane == 0) { red[w * 2] = mn; red[w * 2 + 1] = mx; }
        asm volatile("s_waitcnt lgkmcnt(0)" ::: "memory");
        __builtin_amdgcn_sched_barrier(0);
        __builtin_amdgcn_s_barrier();
        mn = fminf(fminf(red[0], red[2]), fminf(red[4], red[6]));
        mx = fmaxf(fmaxf(red[1], red[3]), fmaxf(red[5], red[7]));
    }

    float nm0 = -((x0 >= 0.f) ? x0 * mx : x0 * mn);
    float nm1 = -((x1 >= 0.f) ? x1 * mx : x1 * mn);
    float wpadf0, wpadf1;
    {
        half2v p0 = pkrtz(__builtin_amdgcn_exp2f(nm0), 0.f);
        half2v p1 = pkrtz(__builtin_amdgcn_exp2f(nm1), 0.f);
        wpadf0 = (float)p0[0];
        wpadf1 = (float)p1[0];
    }

    f32x4 acc0[8], acc1[8];
    #pragma unroll
    for (int e = 0; e < 8; ++e) {
        acc0[e] = (f32x4){0.f, 0.f, 0.f, 0.f};
        acc1[e] = (f32x4){0.f, 0.f, 0.f, 0.f};
    }
    f32x4 accd0 = (f32x4){0.f, 0.f, 0.f, 0.f};
    f32x4 accd1 = (f32x4){0.f, 0.f, 0.f, 0.f};
    half8 ones;
    #pragma unroll
    for (int j = 0; j < 8; ++j) ones[j] = (_Float16)1.0f;

    const float* kvp = Krow + q * 8;   // LDS — P-gen never touches vmcnt
    half8 afrA0, afrA1, afrB0, afrB1;
    compute_afr(kvp, x0, x1, nm0, nm1, afrA0, afrA1);

    const int bofs0 = l15 * 128 + ((q * 16) ^ ((l15 & 7) << 4));
    const int bofs1 = l15 * 128 + ((64 + q * 16) ^ ((l15 & 7) << 4));

#define PVSTEP(AF0, AF1, BOFS) do { \
        __builtin_amdgcn_s_setprio(1); \
        _Pragma("unroll") \
        for (int e = 0; e < 8; ++e) { \
            half8 bfv = *(const half8*)(cb + e * 2048 + (BOFS)); \
            acc0[e] = __builtin_amdgcn_mfma_f32_16x16x32_f16(AF0, bfv, acc0[e], 0, 0, 0); \
            acc1[e] = __builtin_amdgcn_mfma_f32_16x16x32_f16(AF1, bfv, acc1[e], 0, 0, 0); \
        } \
        accd0 = __builtin_amdgcn_mfma_f32_16x16x32_f16(AF0, ones, accd0, 0, 0, 0); \
        accd1 = __builtin_amdgcn_mfma_f32_16x16x32_f16(AF1, ones, accd1, 0, 0, 0); \
        __builtin_amdgcn_s_setprio(0); } while (0)

    #pragma unroll
    for (int kt = 0; kt < 16; ++kt) {
        // chunk kt landed? (chunks kt+1, kt+2 may stay in flight — never drain mid-loop)
        if (kt == 15) asm volatile("s_waitcnt vmcnt(0)" ::: "memory");
        else         asm volatile("s_waitcnt vmcnt(4)" ::: "memory");
        __builtin_amdgcn_sched_barrier(0);
        __builtin_amdgcn_s_barrier();    // publishes chunk kt; licenses overwrite of buf (kt+2)%3
        if (kt < 14) {
            char* d = (char*)&Vs[0][0] + ((kt + 2) % 3) * 16384 + w * 1024;
            #pragma unroll
            for (int i = 0; i < 4; ++i)
                gload_lds16(gsrc + (size_t)(i * 32) * S_PAD + (kt + 2) * 64, d + i * 4096);
        }
        const char* cb = (const char*)&Vs[0][0] + (kt % 3) * 16384;
        compute_afr(kvp + kt * 64 + 32, x0, x1, nm0, nm1, afrB0, afrB1);
        PVSTEP(afrA0, afrA1, bofs0);
        if (kt < 15) compute_afr(kvp + (kt + 1) * 64, x0, x1, nm0, nm1, afrA0, afrA1);
        PVSTEP(afrB0, afrB1, bofs1);
    }
#undef PVSTEP

    // epilogue: den = rowsum - 24 * wpad(row)
    int rowoff = q << 2;
    #pragma unroll
    for (int r = 0; r < 2; ++r) {
        #pragma unroll
        for (int qq = 0; qq < 4; ++qq) {
            float wp = __shfl(r ? wpadf1 : wpadf0, rowoff + qq);
            float den = (r ? accd1[qq] : accd0[qq]) - 24.f * wp;
            float inv = 1.f / den;
            int mrow = m0 + r * 16 + rowoff + qq;
            _Float16* op = attB + (size_t)mrow * DKH + h * DK + l15;
            #pragma unroll
            for (int e = 0; e < 8; ++e)
                op[e * 16] = (_Float16)((r ? acc1[e][qq] : acc0[e][qq]) * inv);
        }
    }
}

// ================= out projection: 128x96 tiles, 3-buffer, 1 barrier/k-step =================
__global__ __launch_bounds__(256) void outproj_kernel(const _Float16* __restrict__ A,
                                                      const _Float16* __restrict__ Bt,
                                                      const float* __restrict__ bo,
                                                      float* __restrict__ C) {
    __shared__ _Float16 As[3][4096];   // 3 x 8KB
    __shared__ _Float16 Bs[3][3072];   // 3 x 6KB
    int wg = blockIdx.x;
    wg = (wg & 7) * 96 + (wg >> 3);            // bijective XCD chunking (768 % 8 == 0)
    int bx = wg & 7, by = wg >> 3;
    int t = threadIdx.x, w = t >> 6, lane = t & 63;
    int bm0 = by * 128, bn0 = bx * 96;
    int lrow = t >> 2, lcol = (t & 3) * 8;
    const _Float16* ga0 = A + (size_t)(bm0 + lrow) * DKH + lcol;
    const _Float16* ga1 = ga0 + (size_t)64 * DKH;
    const _Float16* gb0 = Bt + (size_t)(bn0 + lrow) * DKH + lcol;
    const _Float16* gb1 = gb0 + (size_t)64 * DKH;   // rows 64..95: waves 0-1 only

    f32x4 acc[4][3];
    #pragma unroll
    for (int m = 0; m < 4; ++m)
        #pragma unroll
        for (int n = 0; n < 3; ++n) acc[m][n] = (f32x4){0.f, 0.f, 0.f, 0.f};

    int sgrp = (lane >> 4) << 3;
    int arow = (w >> 1) * 64 + (lane & 15);
    int brow = (w & 1) * 48 + (lane & 15);

#define OSTAGE(bi, k0) do { \
        gload_lds16(ga0 + (k0), (char*)&As[bi][0] + w * 1024); \
        gload_lds16(ga1 + (k0), (char*)&As[bi][0] + 4096 + w * 1024); \
        gload_lds16(gb0 + (k0), (char*)&Bs[bi][0] + w * 1024); \
        if (w < 2) gload_lds16(gb1 + (k0), (char*)&Bs[bi][0] + 4096 + w * 1024); } while (0)

    OSTAGE(0, 0);
    OSTAGE(1, 32);
    #pragma unroll
    for (int kt = 0; kt < 32; ++kt) {
        if (kt == 31)   asm volatile("s_waitcnt vmcnt(0)" ::: "memory");
        else if (w < 2) asm volatile("s_waitcnt vmcnt(4)" ::: "memory");
        else            asm volatile("s_waitcnt vmcnt(3)" ::: "memory");
        __builtin_amdgcn_sched_barrier(0);
        __builtin_amdgcn_s_barrier();
        if (kt < 30) OSTAGE((kt + 2) % 3, (kt + 2) * 32);
        const _Float16* Ac = &As[kt % 3][0];
        const _Float16* Bc = &Bs[kt % 3][0];
        half8 af[4], bf[3];
        #pragma unroll
        for (int m = 0; m < 4; ++m) af[m] = *(const half8*)(Ac + (arow + m * 16) * 32 + sgrp);
        #pragma unroll
        for (int n = 0; n < 3; ++n) bf[n] = *(const half8*)(Bc + (brow + n * 16) * 32 + sgrp);
        __builtin_amdgcn_s_setprio(1);
        #pragma unroll
        for (int m = 0; m < 4; ++m)
            #pragma unroll
            for (int n = 0; n < 3; ++n)
                acc[m][n] = __builtin_amdgcn_mfma_f32_16x16x32_f16(af[m], bf[n], acc[m][n], 0, 0, 0);
        __builtin_amdgcn_s_setprio(0);
    }
#undef OSTAGE

    int rowoff = (lane >> 4) << 2;
    #pragma unroll
    for (int m = 0; m < 4; ++m) {
        #pragma unroll
        for (int n = 0; n < 3; ++n) {
            int col = bn0 + (w & 1) * 48 + n * 16 + (lane & 15);
            float b = bo[col];
            #pragma unroll
            for (int q = 0; q < 4; ++q) {
                int row = bm0 + (w >> 1) * 64 + m * 16 + rowoff + q;
                C[(size_t)row * D_LLM + col] = acc[m][n][q] + b;
            }
        }
    }
}

extern "C" void kernel_launch(void* const* d_in, const int* in_sizes, int n_in,
                              void* d_out, int out_size, void* d_ws, size_t ws_size,
                              hipStream_t stream) {
    const float* ts   = (const float*)d_in[0];
    const float* src  = (const float*)d_in[1];
    const float* vemb = (const float*)d_in[2];
    const float* Wk   = (const float*)d_in[3];
    const float* bk   = (const float*)d_in[4];
    const float* Wv   = (const float*)d_in[5];
    const float* bv   = (const float*)d_in[6];
    const float* Wo   = (const float*)d_in[7];
    const float* bo   = (const float*)d_in[8];
    float* out = (float*)d_out;

    // workspace layout (float offsets, 16B aligned)
    float* ws = (float*)d_ws;
    float* Kpad   = ws;                               // 8192 f
    float* Wksum  = ws + 8192;                        // 6144 f
    float* bksum  = ws + 14336;                       // 16 f
    _Float16* Vt   = (_Float16*)(ws + 14592);         // 1024*1024 f16
    _Float16* Wot  = (_Float16*)(ws + 540672);        // 768*1024 f16
    _Float16* attB = (_Float16*)(ws + 936960);        // 12288*1024 f16
    // vproj prep buffers alias attB region (dead before attn writes attB)
    _Float16* Ab16 = (_Float16*)(ws + 936960);        // 1024*768 f16
    _Float16* Wvt  = (_Float16*)(ws + 1330176);       // 1024*768 f16

    // 1) prep: vemb->f16, Wv^T, Wo^T, Wksum/bksum
    prep_kernel<<<2497, 256, 0, stream>>>(vemb, Wv, Wo, Wk, bk, Ab16, Wvt, Wot, Wksum, bksum);
    // 2) merged ksum + vproj
    kv_kernel<<<512, 256, 0, stream>>>(src, Wksum, bksum, Kpad, Ab16, Wvt, bv, Vt);
    // 3) fused softmax + PV (f16 MFMA, 3-buf counted-vmcnt, in-kernel minmax)
    {
        dim3 g(96, NH);
        attn_mfma_kernel<<<g, 256, 0, stream>>>(ts, Kpad, Vt, attB);
    }
    // 4) out projection: [12288,1024]@[1024,768] + bo
    outproj_kernel<<<768, 256, 0, stream>>>(attB, Wot, bo, out);
}

// Round 14
// 86.757 us; speedup vs baseline: 1.3393x; 1.0111x over previous
//
#include <hip/hip_runtime.h>
#include <hip/hip_bf16.h>
#include <math.h>

#define D_LLM 768
#define DKH   1024   // d_keys * n_heads = 128*8
#define NH    8
#define DK    128
#define S_LEN 1000
#define S_PAD 1024
#define M_ROWS 12288 // B*N*T = 128*96
#define T_LEN 96
#define N_VARS 16

static constexpr float SCALE_EXP2 = (float)(0.08838834764831845 * 1.4426950408889634); // 1/sqrt(128)/ln2

typedef __attribute__((ext_vector_type(8))) _Float16 half8;
typedef __attribute__((ext_vector_type(2))) _Float16 half2v;
typedef __attribute__((ext_vector_type(4))) float f32x4;

__device__ __forceinline__ half2v pkrtz(float a, float b) {
    return __builtin_bit_cast(half2v, __builtin_amdgcn_cvt_pkrtz(a, b));
}

__device__ __forceinline__ void gload_lds16(const void* g, void* l) {
    __builtin_amdgcn_global_load_lds(
        (const __attribute__((address_space(1))) unsigned int*)g,
        (__attribute__((address_space(3))) unsigned int*)l, 16, 0, 0);
}

// ================= prep: vemb->f16 | Wv^T->f16 | Wo^T->f16 | Wksum =================
__global__ __launch_bounds__(256) void prep_kernel(const float* __restrict__ vemb,
                                                   const float* __restrict__ Wv,
                                                   const float* __restrict__ Wo,
                                                   const float* __restrict__ Wk,
                                                   const float* __restrict__ bk,
                                                   _Float16* __restrict__ Ab16,
                                                   _Float16* __restrict__ Wvt,
                                                   _Float16* __restrict__ Wot,
                                                   float* __restrict__ Wksum,
                                                   float* __restrict__ bksum) {
    __shared__ float tl[32][33];
    int blk = blockIdx.x, tid = threadIdx.x;
    if (blk < 768) {
        int i4 = (blk * 256 + tid) * 4;
        float4 v = make_float4(0.f, 0.f, 0.f, 0.f);
        if (i4 < S_LEN * D_LLM) v = *(const float4*)(vemb + i4);
        short4 o;
        o.x = __builtin_bit_cast(short, (_Float16)v.x);
        o.y = __builtin_bit_cast(short, (_Float16)v.y);
        o.z = __builtin_bit_cast(short, (_Float16)v.z);
        o.w = __builtin_bit_cast(short, (_Float16)v.w);
        *(short4*)(Ab16 + i4) = o;
    } else if (blk < 1536) {
        int tau = blk - 768;
        int k0 = (tau % 24) * 32, n0 = (tau / 24) * 32;
        int tx = tid & 31, ty = tid >> 5;
        #pragma unroll
        for (int p = 0; p < 4; ++p)
            tl[ty + p * 8][tx] = Wv[(size_t)(k0 + ty + p * 8) * DKH + n0 + tx];
        __syncthreads();
        #pragma unroll
        for (int p = 0; p < 4; ++p)
            Wvt[(size_t)(n0 + ty + p * 8) * D_LLM + k0 + tx] = (_Float16)tl[tx][ty + p * 8];
    } else if (blk < 2304) {
        int tau = blk - 1536;
        int k0 = (tau & 31) * 32, n0 = (tau >> 5) * 32;
        int tx = tid & 31, ty = tid >> 5;
        #pragma unroll
        for (int p = 0; p < 4; ++p)
            tl[ty + p * 8][tx] = Wo[(size_t)(k0 + ty + p * 8) * D_LLM + n0 + tx];
        __syncthreads();
        #pragma unroll
        for (int p = 0; p < 4; ++p)
            Wot[(size_t)(n0 + ty + p * 8) * DKH + k0 + tx] = (_Float16)tl[tx][ty + p * 8];
    } else {
        int blk2 = blk - 2304;
        int w = tid >> 6, lane = tid & 63;
        if (blk2 < 192) {
            int d = blk2 * 4 + w;
            const float* p = Wk + (size_t)d * DKH + lane * 16;
            float s = 0.f;
            #pragma unroll
            for (int i = 0; i < 4; ++i) {
                float4 v = *(const float4*)(p + i * 4);
                s += v.x + v.y + v.z + v.w;
            }
            s += __shfl_down(s, 4);
            s += __shfl_down(s, 2);
            s += __shfl_down(s, 1);
            if ((lane & 7) == 0) Wksum[d * NH + (lane >> 3)] = s;
        } else if (w == 0) {
            const float* p = bk + lane * 16;
            float s = 0.f;
            #pragma unroll
            for (int i = 0; i < 4; ++i) {
                float4 v = *(const float4*)(p + i * 4);
                s += v.x + v.y + v.z + v.w;
            }
            s += __shfl_down(s, 4);
            s += __shfl_down(s, 2);
            s += __shfl_down(s, 1);
            if ((lane & 7) == 0) bksum[lane >> 3] = s;
        }
    }
}

// ================= merged: ksum (blocks 0-255) + vproj (blocks 256-511) =================
__global__ __launch_bounds__(256) void kv_kernel(const float* __restrict__ src,
                                                 const float* __restrict__ Wksum,
                                                 const float* __restrict__ bksum,
                                                 float* __restrict__ Kpad,
                                                 const _Float16* __restrict__ A,
                                                 const _Float16* __restrict__ Bt,
                                                 const float* __restrict__ bias,
                                                 _Float16* __restrict__ Vt) {
    __shared__ _Float16 VAs[2][2048];
    __shared__ _Float16 VBs[2][2048];
    int tid = threadIdx.x;
    if (blockIdx.x < 256) {
        // ---- ksum: Kpad[h][s] = (src[s,:].Wksum[:,h] + bksum[h]) * SCALE_EXP2 ----
        int w = tid >> 6, lane = tid & 63;
        int s = blockIdx.x * 4 + w;
        if (s >= S_LEN) {
            if (lane < 8) Kpad[lane * S_PAD + s] = 0.f;
            return;
        }
        const float* sp = src + (size_t)s * D_LLM + lane * 12;
        float xv[12];
        ((float4*)xv)[0] = *(const float4*)(sp);
        ((float4*)xv)[1] = *(const float4*)(sp + 4);
        ((float4*)xv)[2] = *(const float4*)(sp + 8);
        float a[8] = {0.f, 0.f, 0.f, 0.f, 0.f, 0.f, 0.f, 0.f};
        const float* wp = Wksum + lane * 12 * NH;
        #pragma unroll
        for (int i = 0; i < 12; ++i) {
            float4 wa = *(const float4*)(wp + i * 8);
            float4 wb = *(const float4*)(wp + i * 8 + 4);
            a[0] = fmaf(xv[i], wa.x, a[0]); a[1] = fmaf(xv[i], wa.y, a[1]);
            a[2] = fmaf(xv[i], wa.z, a[2]); a[3] = fmaf(xv[i], wa.w, a[3]);
            a[4] = fmaf(xv[i], wb.x, a[4]); a[5] = fmaf(xv[i], wb.y, a[5]);
            a[6] = fmaf(xv[i], wb.z, a[6]); a[7] = fmaf(xv[i], wb.w, a[7]);
        }
        #pragma unroll
        for (int off = 32; off > 0; off >>= 1) {
            #pragma unroll
            for (int hh = 0; hh < 8; ++hh) a[hh] += __shfl_xor(a[hh], off);
        }
        #pragma unroll
        for (int hh = 0; hh < 8; ++hh)
            if (lane == hh) Kpad[hh * S_PAD + s] = (a[hh] + bksum[hh]) * SCALE_EXP2;
        return;
    }
    // ---- vproj: 64x64 tiles ----
    int b2 = blockIdx.x - 256;
    int w = tid >> 6, lane = tid & 63;
    int bm0 = (b2 >> 4) * 64, bn0 = (b2 & 15) * 64;
    int lrow = tid >> 2, lcol = (tid & 3) * 8;
    const _Float16* ga = A + (size_t)(bm0 + lrow) * D_LLM + lcol;
    const _Float16* gb = Bt + (size_t)(bn0 + lrow) * D_LLM + lcol;

    f32x4 acc[2][2];
    #pragma unroll
    for (int m = 0; m < 2; ++m)
        #pragma unroll
        for (int n = 0; n < 2; ++n) acc[m][n] = (f32x4){0.f, 0.f, 0.f, 0.f};
    int sgrp = (lane >> 4) << 3;
    int arow = (w >> 1) * 32 + (lane & 15);
    int brow = (w & 1) * 32 + (lane & 15);

#define VSTAGE(buf, k0) do { \
        gload_lds16(ga + (k0), (char*)&VAs[buf][0] + w * 1024); \
        gload_lds16(gb + (k0), (char*)&VBs[buf][0] + w * 1024); } while (0)

    VSTAGE(0, 0);
    __syncthreads();
    #pragma unroll 2
    for (int tt = 0; tt < 24; ++tt) {
        int cur = tt & 1;
        if (tt < 23) VSTAGE(cur ^ 1, (tt + 1) * 32);
        const _Float16* Ac = &VAs[cur][0];
        const _Float16* Bc = &VBs[cur][0];
        half8 af[2], bf[2];
        #pragma unroll
        for (int m = 0; m < 2; ++m) af[m] = *(const half8*)(Ac + (arow + m * 16) * 32 + sgrp);
        #pragma unroll
        for (int n = 0; n < 2; ++n) bf[n] = *(const half8*)(Bc + (brow + n * 16) * 32 + sgrp);
        __builtin_amdgcn_s_setprio(1);
        #pragma unroll
        for (int m = 0; m < 2; ++m)
            #pragma unroll
            for (int n = 0; n < 2; ++n)
                acc[m][n] = __builtin_amdgcn_mfma_f32_16x16x32_f16(af[m], bf[n], acc[m][n], 0, 0, 0);
        __builtin_amdgcn_s_setprio(0);
        __syncthreads();
    }
#undef VSTAGE

    int rowoff = (lane >> 4) << 2;
    #pragma unroll
    for (int m = 0; m < 2; ++m) {
        #pragma unroll
        for (int n = 0; n < 2; ++n) {
            int c = bn0 + (w & 1) * 32 + n * 16 + (lane & 15);
            float b = bias[c];
            #pragma unroll
            for (int q = 0; q < 4; ++q) {
                int srow = bm0 + (w >> 1) * 32 + m * 16 + rowoff + q;
                float val = (srow < S_LEN) ? acc[m][n][q] + b : 0.f;
                Vt[(size_t)c * S_PAD + srow] = (_Float16)val;
            }
        }
    }
}

// ================= fused softmax + PV: 48 rows/wave, 3-buffer, 1 barrier/chunk =================
__device__ __forceinline__ void compute_afr3(const float* kq, const float* x, const float* nm,
                                             half8* o) {
    float4 a = *(const float4*)kq;        // ds_read_b128 (LDS)
    float4 b = *(const float4*)(kq + 4);
    float kv[8] = {a.x, a.y, a.z, a.w, b.x, b.y, b.z, b.w};
    #pragma unroll
    for (int r = 0; r < 3; ++r) {
        union { half8 v; half2v hh[4]; } u;
        #pragma unroll
        for (int j = 0; j < 4; ++j) {
            float w0 = __builtin_amdgcn_exp2f(fmaf(x[r], kv[2 * j], nm[r]));
            float w1 = __builtin_amdgcn_exp2f(fmaf(x[r], kv[2 * j + 1], nm[r]));
            u.hh[j] = pkrtz(w0, w1);
        }
        o[r] = u.v;
    }
}

__global__ __launch_bounds__(256) void attn_mfma_kernel(const float* __restrict__ ts,
                                                        const float* __restrict__ Kpad,
                                                        const _Float16* __restrict__ Vt,
                                                        _Float16* __restrict__ attB) {
    __shared__ _Float16 Vs[3][8192];   // 3 x 16KB chunks (64 s x 128 e, XOR-swizzled rows)
    __shared__ float Krow[1024];       // this head's scaled K row (4KB)
    __shared__ float red[8];
    const int tid = threadIdx.x;
    const int lane = tid & 63, w = tid >> 6;
    const int h = blockIdx.y;
    const int m0 = (blockIdx.x * 4 + w) * 48;   // 48 rows per wave, 192 per block
    const int l15 = lane & 15, q = lane >> 4;

    const int erow = w * 8 + (lane >> 3);
    const int sgl = ((lane & 7) ^ (lane >> 3)) * 8;
    const _Float16* gsrc = Vt + (size_t)(h * DK + erow) * S_PAD + sgl;
    const float* kg = Kpad + h * S_PAD;

    // issue Krow stage first (oldest), then V chunks 0,1
    gload_lds16(kg + w * 256 + lane * 4, (char*)Krow + w * 1024);
    #pragma unroll
    for (int i = 0; i < 4; ++i)
        gload_lds16(gsrc + (size_t)(i * 32) * S_PAD, (char*)&Vs[0][0] + i * 4096 + w * 1024);
    #pragma unroll
    for (int i = 0; i < 4; ++i)
        gload_lds16(gsrc + (size_t)(i * 32) * S_PAD + 64, (char*)&Vs[1][0] + i * 4096 + w * 1024);

    float x[3];
    #pragma unroll
    for (int r = 0; r < 3; ++r) {
        int m = m0 + r * 16 + l15;
        int rr = m / T_LEN;
        float v = ts[((size_t)(rr >> 4) * T_LEN + (m % T_LEN)) * N_VARS + (rr & 15)];
        x[r] = (v != v) ? 0.f : v;
    }

    asm volatile("s_waitcnt vmcnt(8)" ::: "memory");   // Krow landed (V chunks may still fly)
    __builtin_amdgcn_sched_barrier(0);
    __builtin_amdgcn_s_barrier();

    // per-head min/max from LDS row (s<1000 only; pads are 0)
    float mn, mx;
    {
        float4 k4 = *(const float4*)&Krow[tid * 4];
        if (tid < 250) {
            mx = fmaxf(fmaxf(k4.x, k4.y), fmaxf(k4.z, k4.w));
            mn = fminf(fminf(k4.x, k4.y), fminf(k4.z, k4.w));
        } else { mx = -3e38f; mn = 3e38f; }
        #pragma unroll
        for (int off = 32; off > 0; off >>= 1) {
            mx = fmaxf(mx, __shfl_xor(mx, off));
            mn = fminf(mn, __shfl_xor(mn, off));
        }
        if (lane == 0) { red[w * 2] = mn; red[w * 2 + 1] = mx; }
        asm volatile("s_waitcnt lgkmcnt(0)" ::: "memory");
        __builtin_amdgcn_sched_barrier(0);
        __builtin_amdgcn_s_barrier();
        mn = fminf(fminf(red[0], red[2]), fminf(red[4], red[6]));
        mx = fmaxf(fmaxf(red[1], red[3]), fmaxf(red[5], red[7]));
    }

    float nm[3], wpadf[3];
    #pragma unroll
    for (int r = 0; r < 3; ++r) {
        nm[r] = -((x[r] >= 0.f) ? x[r] * mx : x[r] * mn);
        half2v p = pkrtz(__builtin_amdgcn_exp2f(nm[r]), 0.f);
        wpadf[r] = (float)p[0];
    }

    f32x4 acc[3][8];
    #pragma unroll
    for (int r = 0; r < 3; ++r)
        #pragma unroll
        for (int e = 0; e < 8; ++e) acc[r][e] = (f32x4){0.f, 0.f, 0.f, 0.f};
    f32x4 accd[3];
    #pragma unroll
    for (int r = 0; r < 3; ++r) accd[r] = (f32x4){0.f, 0.f, 0.f, 0.f};
    half8 ones;
    #pragma unroll
    for (int j = 0; j < 8; ++j) ones[j] = (_Float16)1.0f;

    const float* kvp = Krow + q * 8;   // LDS — P-gen never touches vmcnt
    half8 afrA[3], afrB[3];
    compute_afr3(kvp, x, nm, afrA);

    const int bofs0 = l15 * 128 + ((q * 16) ^ ((l15 & 7) << 4));
    const int bofs1 = l15 * 128 + ((64 + q * 16) ^ ((l15 & 7) << 4));

#define PVSTEP(AF, BOFS) do { \
        __builtin_amdgcn_s_setprio(1); \
        _Pragma("unroll") \
        for (int e = 0; e < 8; ++e) { \
            half8 bfv = *(const half8*)(cb + e * 2048 + (BOFS)); \
            _Pragma("unroll") \
            for (int r = 0; r < 3; ++r) \
                acc[r][e] = __builtin_amdgcn_mfma_f32_16x16x32_f16(AF[r], bfv, acc[r][e], 0, 0, 0); \
        } \
        _Pragma("unroll") \
        for (int r = 0; r < 3; ++r) \
            accd[r] = __builtin_amdgcn_mfma_f32_16x16x32_f16(AF[r], ones, accd[r], 0, 0, 0); \
        __builtin_amdgcn_s_setprio(0); } while (0)

    #pragma unroll
    for (int kt = 0; kt < 16; ++kt) {
        if (kt == 15) asm volatile("s_waitcnt vmcnt(0)" ::: "memory");
        else          asm volatile("s_waitcnt vmcnt(4)" ::: "memory");
        __builtin_amdgcn_sched_barrier(0);
        __builtin_amdgcn_s_barrier();    // publishes chunk kt; licenses overwrite of buf (kt+2)%3
        if (kt < 14) {
            char* d = (char*)&Vs[0][0] + ((kt + 2) % 3) * 16384 + w * 1024;
            #pragma unroll
            for (int i = 0; i < 4; ++i)
                gload_lds16(gsrc + (size_t)(i * 32) * S_PAD + (kt + 2) * 64, d + i * 4096);
        }
        const char* cb = (const char*)&Vs[0][0] + (kt % 3) * 16384;
        compute_afr3(kvp + kt * 64 + 32, x, nm, afrB);
        PVSTEP(afrA, bofs0);
        if (kt < 15) compute_afr3(kvp + (kt + 1) * 64, x, nm, afrA);
        PVSTEP(afrB, bofs1);
    }
#undef PVSTEP

    // epilogue: den = rowsum - 24 * wpad(row)
    int rowoff = q << 2;
    #pragma unroll
    for (int r = 0; r < 3; ++r) {
        #pragma unroll
        for (int qq = 0; qq < 4; ++qq) {
            float wp = __shfl(wpadf[r], rowoff + qq);
            float den = accd[r][qq] - 24.f * wp;
            float inv = 1.f / den;
            int mrow = m0 + r * 16 + rowoff + qq;
            _Float16* op = attB + (size_t)mrow * DKH + h * DK + l15;
            #pragma unroll
            for (int e = 0; e < 8; ++e)
                op[e * 16] = (_Float16)(acc[r][e][qq] * inv);
        }
    }
}

// ================= out projection: 128x96 tiles, 3-buffer, 1 barrier/k-step =================
__global__ __launch_bounds__(256) void outproj_kernel(const _Float16* __restrict__ A,
                                                      const _Float16* __restrict__ Bt,
                                                      const float* __restrict__ bo,
                                                      float* __restrict__ C) {
    __shared__ _Float16 As[3][4096];   // 3 x 8KB
    __shared__ _Float16 Bs[3][3072];   // 3 x 6KB
    int wg = blockIdx.x;
    wg = (wg & 7) * 96 + (wg >> 3);            // bijective XCD chunking (768 % 8 == 0)
    int bx = wg & 7, by = wg >> 3;
    int t = threadIdx.x, w = t >> 6, lane = t & 63;
    int bm0 = by * 128, bn0 = bx * 96;
    int lrow = t >> 2, lcol = (t & 3) * 8;
    const _Float16* ga0 = A + (size_t)(bm0 + lrow) * DKH + lcol;
    const _Float16* ga1 = ga0 + (size_t)64 * DKH;
    const _Float16* gb0 = Bt + (size_t)(bn0 + lrow) * DKH + lcol;
    const _Float16* gb1 = gb0 + (size_t)64 * DKH;   // rows 64..95: waves 0-1 only

    f32x4 acc[4][3];
    #pragma unroll
    for (int m = 0; m < 4; ++m)
        #pragma unroll
        for (int n = 0; n < 3; ++n) acc[m][n] = (f32x4){0.f, 0.f, 0.f, 0.f};

    int sgrp = (lane >> 4) << 3;
    int arow = (w >> 1) * 64 + (lane & 15);
    int brow = (w & 1) * 48 + (lane & 15);

#define OSTAGE(bi, k0) do { \
        gload_lds16(ga0 + (k0), (char*)&As[bi][0] + w * 1024); \
        gload_lds16(ga1 + (k0), (char*)&As[bi][0] + 4096 + w * 1024); \
        gload_lds16(gb0 + (k0), (char*)&Bs[bi][0] + w * 1024); \
        if (w < 2) gload_lds16(gb1 + (k0), (char*)&Bs[bi][0] + 4096 + w * 1024); } while (0)

    OSTAGE(0, 0);
    OSTAGE(1, 32);
    #pragma unroll
    for (int kt = 0; kt < 32; ++kt) {
        if (kt == 31)   asm volatile("s_waitcnt vmcnt(0)" ::: "memory");
        else if (w < 2) asm volatile("s_waitcnt vmcnt(4)" ::: "memory");
        else            asm volatile("s_waitcnt vmcnt(3)" ::: "memory");
        __builtin_amdgcn_sched_barrier(0);
        __builtin_amdgcn_s_barrier();
        if (kt < 30) OSTAGE((kt + 2) % 3, (kt + 2) * 32);
        const _Float16* Ac = &As[kt % 3][0];
        const _Float16* Bc = &Bs[kt % 3][0];
        half8 af[4], bf[3];
        #pragma unroll
        for (int m = 0; m < 4; ++m) af[m] = *(const half8*)(Ac + (arow + m * 16) * 32 + sgrp);
        #pragma unroll
        for (int n = 0; n < 3; ++n) bf[n] = *(const half8*)(Bc + (brow + n * 16) * 32 + sgrp);
        __builtin_amdgcn_s_setprio(1);
        #pragma unroll
        for (int m = 0; m < 4; ++m)
            #pragma unroll
            for (int n = 0; n < 3; ++n)
                acc[m][n] = __builtin_amdgcn_mfma_f32_16x16x32_f16(af[m], bf[n], acc[m][n], 0, 0, 0);
        __builtin_amdgcn_s_setprio(0);
    }
#undef OSTAGE

    int rowoff = (lane >> 4) << 2;
    #pragma unroll
    for (int m = 0; m < 4; ++m) {
        #pragma unroll
        for (int n = 0; n < 3; ++n) {
            int col = bn0 + (w & 1) * 48 + n * 16 + (lane & 15);
            float b = bo[col];
            #pragma unroll
            for (int q = 0; q < 4; ++q) {
                int row = bm0 + (w >> 1) * 64 + m * 16 + rowoff + q;
                C[(size_t)row * D_LLM + col] = acc[m][n][q] + b;
            }
        }
    }
}

extern "C" void kernel_launch(void* const* d_in, const int* in_sizes, int n_in,
                              void* d_out, int out_size, void* d_ws, size_t ws_size,
                              hipStream_t stream) {
    const float* ts   = (const float*)d_in[0];
    const float* src  = (const float*)d_in[1];
    const float* vemb = (const float*)d_in[2];
    const float* Wk   = (const float*)d_in[3];
    const float* bk   = (const float*)d_in[4];
    const float* Wv   = (const float*)d_in[5];
    const float* bv   = (const float*)d_in[6];
    const float* Wo   = (const float*)d_in[7];
    const float* bo   = (const float*)d_in[8];
    float* out = (float*)d_out;

    // workspace layout (float offsets, 16B aligned)
    float* ws = (float*)d_ws;
    float* Kpad   = ws;                               // 8192 f
    float* Wksum  = ws + 8192;                        // 6144 f
    float* bksum  = ws + 14336;                       // 16 f
    _Float16* Vt   = (_Float16*)(ws + 14592);         // 1024*1024 f16
    _Float16* Wot  = (_Float16*)(ws + 540672);        // 768*1024 f16
    _Float16* attB = (_Float16*)(ws + 936960);        // 12288*1024 f16
    // vproj prep buffers alias attB region (dead before attn writes attB)
    _Float16* Ab16 = (_Float16*)(ws + 936960);        // 1024*768 f16
    _Float16* Wvt  = (_Float16*)(ws + 1330176);       // 1024*768 f16

    // 1) prep: vemb->f16, Wv^T, Wo^T, Wksum/bksum
    prep_kernel<<<2497, 256, 0, stream>>>(vemb, Wv, Wo, Wk, bk, Ab16, Wvt, Wot, Wksum, bksum);
    // 2) merged ksum + vproj
    kv_kernel<<<512, 256, 0, stream>>>(src, Wksum, bksum, Kpad, Ab16, Wvt, bv, Vt);
    // 3) fused softmax + PV (48 rows/wave, 3-buf counted-vmcnt, in-kernel minmax)
    {
        dim3 g(64, NH);
        attn_mfma_kernel<<<g, 256, 0, stream>>>(ts, Kpad, Vt, attB);
    }
    // 4) out projection: [12288,1024]@[1024,768] + bo
    outproj_kernel<<<768, 256, 0, stream>>>(attB, Wot, bo, out);
}